// Round 1
// baseline (229.727 us; speedup 1.0000x reference)
//
#include <hip/hip_runtime.h>

#define SEQ 64
#define D 28
#define EMB 784  // 28*28

typedef float float4v __attribute__((ext_vector_type(4)));

// One block = one wave = one sentence. 7x7 lane grid, each lane owns a 4x4
// tile of the running product C (28x28). Per step:
//   1. write own C-tile TRANSPOSED into LDS (LT[k*28+i] = C[i][k])
//   2. rank-1 updates: acc[r][c] += LT-col-slice[r] * Brow-slice[c]
// B slices are read straight from global (L1-cached), never through LDS.
__global__ __launch_bounds__(64) void w2m_kernel(
    const int* __restrict__ sent,
    const float* __restrict__ table,
    float* __restrict__ out)
{
    __shared__ float LT[EMB] __attribute__((aligned(16)));

    const int lane = threadIdx.x;
    const int b = blockIdx.x;

    int it = lane / 7;
    int jt = lane % 7;
    const bool act = (lane < 49);
    if (!act) { it = 6; jt = 6; }  // clamp: harmless duplicate work, stores masked

    const int myidx = sent[b * SEQ + lane];

    // ---- init: C-tile = word-0 matrix tile ----
    const int idx0 = __shfl(myidx, 0, 64);
    const float* row0 = table + (size_t)idx0 * EMB;
    float4v ct[4];
#pragma unroll
    for (int r = 0; r < 4; ++r)
        ct[r] = *(const float4v*)(row0 + (4 * it + r) * D + 4 * jt);

    // ---- prefetch word-1 row, first 8 k-slices ----
    int idxn = __shfl(myidx, 1, 64);
    const float* rowN = table + (size_t)idxn * EMB;
    float4v nb[8];
#pragma unroll
    for (int k = 0; k < 8; ++k)
        nb[k] = *(const float4v*)(rowN + k * D + 4 * jt);

#pragma unroll 1
    for (int s = 1; s < SEQ; ++s) {
        // 1. publish current product (transposed) to LDS
        if (act) {
#pragma unroll
            for (int c = 0; c < 4; ++c) {
                float4v t;
                t.x = ct[0][c]; t.y = ct[1][c]; t.z = ct[2][c]; t.w = ct[3][c];
                *(float4v*)&LT[(4 * jt + c) * D + 4 * it] = t;
            }
        }
        __builtin_amdgcn_s_waitcnt(0xC07F);  // lgkmcnt(0): LDS writes visible

        const float* rowB = rowN;  // current step's B row (prefetched last iter)

        // 3. issue remaining B loads for current step (k = 8..27)
        float4v bv[20];
#pragma unroll
        for (int k = 0; k < 20; ++k)
            bv[k] = *(const float4v*)(rowB + (k + 8) * D + 4 * jt);

        // 4. compute k = 0..7 from prefetched nb[]
        float4v acc[4];
        {
            float4v av = *(const float4v*)&LT[0 * D + 4 * it];
            float4v bb = nb[0];
#pragma unroll
            for (int r = 0; r < 4; ++r) acc[r] = bb * av[r];
        }
#pragma unroll
        for (int k = 1; k < 8; ++k) {
            float4v av = *(const float4v*)&LT[k * D + 4 * it];
            float4v bb = nb[k];
#pragma unroll
            for (int r = 0; r < 4; ++r) acc[r] += bb * av[r];
        }

        // 5. prefetch next step's B row (k = 0..7) into nb[]
        const int sn = (s + 1 < SEQ) ? (s + 1) : (SEQ - 1);
        idxn = __shfl(myidx, sn, 64);
        rowN = table + (size_t)idxn * EMB;
#pragma unroll
        for (int k = 0; k < 8; ++k)
            nb[k] = *(const float4v*)(rowN + k * D + 4 * jt);

        // 6. compute k = 8..27 from bv[]
#pragma unroll
        for (int k = 8; k < 28; ++k) {
            float4v av = *(const float4v*)&LT[k * D + 4 * it];
            float4v bb = bv[k - 8];
#pragma unroll
            for (int r = 0; r < 4; ++r) acc[r] += bb * av[r];
        }

#pragma unroll
        for (int r = 0; r < 4; ++r) ct[r] = acc[r];
    }

    // ---- store final product tile ----
    if (act) {
        float* orow = out + (size_t)b * EMB;
#pragma unroll
        for (int r = 0; r < 4; ++r)
            *(float4v*)(orow + (4 * it + r) * D + 4 * jt) = ct[r];
    }
}

extern "C" void kernel_launch(void* const* d_in, const int* in_sizes, int n_in,
                              void* d_out, int out_size, void* d_ws, size_t ws_size,
                              hipStream_t stream) {
    const int* sent = (const int*)d_in[0];
    const float* table = (const float*)d_in[1];
    float* out = (float*)d_out;
    const int batch = in_sizes[0] / SEQ;  // 1024
    hipLaunchKernelGGL(w2m_kernel, dim3(batch), dim3(64), 0, stream,
                       sent, table, out);
}

// Round 2
// 205.608 us; speedup vs baseline: 1.1173x; 1.1173x over previous
//
#include <hip/hip_runtime.h>

#define SEQ 64
#define D 28
#define EMB 784  // 28*28
#define CH 8     // leaf chain length per wave

typedef float float4v __attribute__((ext_vector_type(4)));

// One wave multiplies its register-resident product C (28x28, 4x4 tile per
// lane on a 7x7 lane grid) by matrix B (rowB, row-major in global memory):
//   1. publish C^T into this wave's private LDS region (4 ds_write_b128)
//   2. rank-1 updates over k: acc[r][c] += C^T[k][4it+r] * B[k][4jt+c]
//      (28 ds_read_b128 for A-slices, 28 global b128 for B-slices)
__device__ __forceinline__ void chain_step(float4v ct[4],
                                           const float* __restrict__ rowB,
                                           float* __restrict__ LTw,
                                           int it, int jt, bool act)
{
    if (act) {
#pragma unroll
        for (int c = 0; c < 4; ++c) {
            float4v t;
            t.x = ct[0][c]; t.y = ct[1][c]; t.z = ct[2][c]; t.w = ct[3][c];
            *(float4v*)&LTw[(4 * jt + c) * D + 4 * it] = t;
        }
    }
    __builtin_amdgcn_s_waitcnt(0xC07F);  // lgkmcnt(0): LDS writes visible to self

    const float* bp = rowB + 4 * jt;
    const float* ap = LTw + 4 * it;

    float4v acc[4] = {};
    float4v bb0[4], bb1[4];
#pragma unroll
    for (int q = 0; q < 4; ++q) bb0[q] = *(const float4v*)(bp + q * D);

#pragma unroll
    for (int g = 0; g < 7; ++g) {
        if (g < 6) {  // prefetch next k-group of B while computing this one
#pragma unroll
            for (int q = 0; q < 4; ++q)
                ((g & 1) ? bb0 : bb1)[q] = *(const float4v*)(bp + ((g + 1) * 4 + q) * D);
        }
#pragma unroll
        for (int q = 0; q < 4; ++q) {
            const int k = g * 4 + q;
            float4v av = *(const float4v*)(ap + k * D);
            float4v bb = (g & 1) ? bb1[q] : bb0[q];
#pragma unroll
            for (int r = 0; r < 4; ++r) acc[r] += bb * av[r];
        }
    }
#pragma unroll
    for (int r = 0; r < 4; ++r) ct[r] = acc[r];
}

// Leaf: wave w = (sentence b, group g) computes product of words 8g..8g+7.
// 8192 waves -> high occupancy for 56/63 of the matmuls.
__global__ __launch_bounds__(256, 4) void w2m_leaf(
    const int* __restrict__ sent,
    const float* __restrict__ table,
    float* __restrict__ ws0)
{
    __shared__ float LT[4 * EMB] __attribute__((aligned(16)));
    const int lane = threadIdx.x & 63;
    const int wid  = threadIdx.x >> 6;
    const int w = blockIdx.x * 4 + wid;   // 0..8191
    const int b = w >> 3;
    const int g = w & 7;
    int it = lane / 7, jt = lane % 7;
    const bool act = lane < 49;
    if (!act) { it = 6; jt = 6; }
    float* LTw = &LT[wid * EMB];

    const int myidx = sent[b * SEQ + 8 * g + (lane & 7)];

    const int i0 = __shfl(myidx, 0, 64);
    const float* row0 = table + (size_t)i0 * EMB;
    float4v ct[4];
#pragma unroll
    for (int r = 0; r < 4; ++r)
        ct[r] = *(const float4v*)(row0 + (4 * it + r) * D + 4 * jt);

#pragma unroll 1
    for (int j = 1; j < CH; ++j) {
        const int ij = __shfl(myidx, j, 64);
        chain_step(ct, table + (size_t)ij * EMB, LTw, it, jt, act);
    }

    if (act) {
        float* orow = ws0 + (size_t)w * EMB;
#pragma unroll
        for (int r = 0; r < 4; ++r)
            *(float4v*)(orow + (4 * it + r) * D + 4 * jt) = ct[r];
    }
}

// Top: wave b multiplies the 8 partial products of sentence b -> d_out.
__global__ __launch_bounds__(256, 4) void w2m_top(
    const float* __restrict__ ws0,
    float* __restrict__ out)
{
    __shared__ float LT[4 * EMB] __attribute__((aligned(16)));
    const int lane = threadIdx.x & 63;
    const int wid  = threadIdx.x >> 6;
    const int b = blockIdx.x * 4 + wid;   // 0..1023
    int it = lane / 7, jt = lane % 7;
    const bool act = lane < 49;
    if (!act) { it = 6; jt = 6; }
    float* LTw = &LT[wid * EMB];

    const float* base = ws0 + (size_t)b * CH * EMB;
    float4v ct[4];
#pragma unroll
    for (int r = 0; r < 4; ++r)
        ct[r] = *(const float4v*)(base + (4 * it + r) * D + 4 * jt);

#pragma unroll 1
    for (int j = 1; j < CH; ++j)
        chain_step(ct, base + (size_t)j * EMB, LTw, it, jt, act);

    if (act) {
        float* orow = out + (size_t)b * EMB;
#pragma unroll
        for (int r = 0; r < 4; ++r)
            *(float4v*)(orow + (4 * it + r) * D + 4 * jt) = ct[r];
    }
}

// ---- Fallback: round-1 single-kernel serial scan (used if ws too small) ----
__global__ __launch_bounds__(64) void w2m_serial(
    const int* __restrict__ sent,
    const float* __restrict__ table,
    float* __restrict__ out)
{
    __shared__ float LT[EMB] __attribute__((aligned(16)));
    const int lane = threadIdx.x;
    const int b = blockIdx.x;
    int it = lane / 7, jt = lane % 7;
    const bool act = (lane < 49);
    if (!act) { it = 6; jt = 6; }
    const int myidx = sent[b * SEQ + lane];
    const int idx0 = __shfl(myidx, 0, 64);
    const float* row0 = table + (size_t)idx0 * EMB;
    float4v ct[4];
#pragma unroll
    for (int r = 0; r < 4; ++r)
        ct[r] = *(const float4v*)(row0 + (4 * it + r) * D + 4 * jt);
#pragma unroll 1
    for (int s = 1; s < SEQ; ++s) {
        const int ij = __shfl(myidx, s, 64);
        chain_step(ct, table + (size_t)ij * EMB, LT, it, jt, act);
    }
    if (act) {
        float* orow = out + (size_t)b * EMB;
#pragma unroll
        for (int r = 0; r < 4; ++r)
            *(float4v*)(orow + (4 * it + r) * D + 4 * jt) = ct[r];
    }
}

extern "C" void kernel_launch(void* const* d_in, const int* in_sizes, int n_in,
                              void* d_out, int out_size, void* d_ws, size_t ws_size,
                              hipStream_t stream) {
    const int* sent = (const int*)d_in[0];
    const float* table = (const float*)d_in[1];
    float* out = (float*)d_out;
    const int batch = in_sizes[0] / SEQ;                  // 1024
    const size_t ws_needed = (size_t)batch * CH * EMB * sizeof(float);  // 25.7 MB

    if (ws_size >= ws_needed) {
        float* ws0 = (float*)d_ws;
        const int waves1 = batch * CH;                    // 8192
        hipLaunchKernelGGL(w2m_leaf, dim3(waves1 / 4), dim3(256), 0, stream,
                           sent, table, ws0);
        hipLaunchKernelGGL(w2m_top, dim3(batch / 4), dim3(256), 0, stream,
                           ws0, out);
    } else {
        hipLaunchKernelGGL(w2m_serial, dim3(batch), dim3(64), 0, stream,
                           sent, table, out);
    }
}